// Round 1
// baseline (337.997 us; speedup 1.0000x reference)
//
#include <hip/hip_runtime.h>

#define R_ 8
#define N_ 4096
#define D_ 128
#define BM 128
#define BK 32
#define KSPLIT 2
#define LDA 40    // padded row stride (ushorts) for As/Bs tiles
#define LDC 136   // padded row stride for agg staging tile

typedef __attribute__((ext_vector_type(8))) short bf16x8;
typedef __attribute__((ext_vector_type(4))) float f32x4;

__device__ __forceinline__ unsigned short f2bf(float f) {
  unsigned int u = __builtin_bit_cast(unsigned int, f);
  u += 0x7FFFu + ((u >> 16) & 1u);   // RNE
  return (unsigned short)(u >> 16);
}
__device__ __forceinline__ unsigned int pk2(float lo, float hi) {
  return (unsigned int)f2bf(lo) | ((unsigned int)f2bf(hi) << 16);
}

// embT[d][n] = bf16(emb[n][d])
__global__ void k_init_embT(const float* __restrict__ emb, unsigned short* __restrict__ embT) {
  int i = blockIdx.x * 256 + threadIdx.x;       // over N*D
  int n = i >> 7, d = i & 127;
  embT[(size_t)d * N_ + n] = f2bf(emb[i]);
}

// relb = bf16(rel) elementwise, layout preserved [R][D][D]
__global__ void k_init_rel(const float* __restrict__ rel, unsigned short* __restrict__ relb) {
  int i = blockIdx.x * 256 + threadIdx.x;       // over R*D*D
  relb[i] = f2bf(rel[i]);
}

// out = relu(out) in place; embT = bf16(out) transposed for next layer
__global__ void k_epilogue(float* __restrict__ out_acc, unsigned short* __restrict__ embT) {
  int i = blockIdx.x * 256 + threadIdx.x;       // over N*D
  float v = out_acc[i];
  v = v > 0.f ? v : 0.f;
  out_acc[i] = v;
  int n = i >> 7, d = i & 127;
  embT[(size_t)d * N_ + n] = f2bf(v);
}

__global__ __launch_bounds__(256, 2) void gcn_gemm(
    const float* __restrict__ adj,            // [R][N][N] fp32
    const unsigned short* __restrict__ embT,  // [D][N] bf16
    const unsigned short* __restrict__ relb,  // [R][D][D] bf16
    float* __restrict__ out_acc)              // [N][D] fp32, pre-zeroed
{
  __shared__ unsigned short sm[BM * LDC];     // 34816 B; holds As+Bs, reused as Cs
  unsigned short* As = sm;                    // [128][LDA]
  unsigned short* Bs = sm + BM * LDA;         // [128][LDA]

  const int tid  = threadIdx.x;
  const int lane = tid & 63;
  const int w    = tid >> 6;
  const int wr = w >> 1, wc = w & 1;          // 2x2 wave grid, 64x64 each
  const int fr  = lane & 15;
  const int k8  = (lane >> 4) * 8;
  const int cr4 = (lane >> 4) * 4;

  const int row0 = blockIdx.x * BM;
  const int r    = blockIdx.y;
  const int k0   = blockIdx.z * (N_ / KSPLIT);
  const int k1   = k0 + N_ / KSPLIT;

  // staging map: 2 threads per row, 16 elements (of 32) each
  const int srow = tid >> 1;
  const int scol = (tid & 1) * 16;

  const float*          gA = adj  + ((size_t)r * N_ + (row0 + srow)) * N_ + scol;
  const unsigned short* gB = embT + (size_t)srow * N_ + scol;

  float4 la0, la1, la2, la3;
  uint4  lb0, lb1;
  {
    const float* p = gA + k0;
    la0 = *(const float4*)(p);
    la1 = *(const float4*)(p + 4);
    la2 = *(const float4*)(p + 8);
    la3 = *(const float4*)(p + 12);
    const unsigned short* q = gB + k0;
    lb0 = *(const uint4*)(q);
    lb1 = *(const uint4*)(q + 8);
  }

  f32x4 acc[4][4];
#pragma unroll
  for (int m = 0; m < 4; ++m)
#pragma unroll
    for (int n = 0; n < 4; ++n)
      acc[m][n] = (f32x4){0.f, 0.f, 0.f, 0.f};

  for (int kk = k0; kk < k1; kk += BK) {
    // write staged registers to LDS (fp32 -> bf16 for A)
    uint4 pa, pb;
    pa.x = pk2(la0.x, la0.y); pa.y = pk2(la0.z, la0.w);
    pa.z = pk2(la1.x, la1.y); pa.w = pk2(la1.z, la1.w);
    pb.x = pk2(la2.x, la2.y); pb.y = pk2(la2.z, la2.w);
    pb.z = pk2(la3.x, la3.y); pb.w = pk2(la3.z, la3.w);
    *(uint4*)&As[srow * LDA + scol]     = pa;
    *(uint4*)&As[srow * LDA + scol + 8] = pb;
    *(uint4*)&Bs[srow * LDA + scol]     = lb0;
    *(uint4*)&Bs[srow * LDA + scol + 8] = lb1;
    __syncthreads();

    // prefetch next K-tile while computing this one
    if (kk + BK < k1) {
      const float* p = gA + kk + BK;
      la0 = *(const float4*)(p);
      la1 = *(const float4*)(p + 4);
      la2 = *(const float4*)(p + 8);
      la3 = *(const float4*)(p + 12);
      const unsigned short* q = gB + kk + BK;
      lb0 = *(const uint4*)(q);
      lb1 = *(const uint4*)(q + 8);
    }

    bf16x8 af[4], bfr[4];
#pragma unroll
    for (int m = 0; m < 4; ++m)
      af[m] = *(const bf16x8*)&As[(wr * 64 + m * 16 + fr) * LDA + k8];
#pragma unroll
    for (int n = 0; n < 4; ++n)
      bfr[n] = *(const bf16x8*)&Bs[(wc * 64 + n * 16 + fr) * LDA + k8];
#pragma unroll
    for (int m = 0; m < 4; ++m)
#pragma unroll
      for (int n = 0; n < 4; ++n)
        acc[m][n] = __builtin_amdgcn_mfma_f32_16x16x32_bf16(af[m], bfr[n], acc[m][n], 0, 0, 0);
    __syncthreads();
  }

  // ---- second GEMM: tmp = agg @ rel^T (K = D = 128, fully local) ----
  unsigned short* Cs = sm;   // [128][LDC]
#pragma unroll
  for (int m = 0; m < 4; ++m)
#pragma unroll
    for (int n = 0; n < 4; ++n)
#pragma unroll
      for (int j = 0; j < 4; ++j)
        Cs[(wr * 64 + m * 16 + cr4 + j) * LDC + wc * 64 + n * 16 + fr] = f2bf(acc[m][n][j]);
  __syncthreads();

  f32x4 tacc[4][4];
#pragma unroll
  for (int m = 0; m < 4; ++m)
#pragma unroll
    for (int n = 0; n < 4; ++n)
      tacc[m][n] = (f32x4){0.f, 0.f, 0.f, 0.f};

  const unsigned short* relr = relb + r * D_ * D_;
#pragma unroll
  for (int es = 0; es < 4; ++es) {
    const int e0 = es * 32 + k8;
    bf16x8 a2[4], b2[4];
#pragma unroll
    for (int m = 0; m < 4; ++m)
      a2[m] = *(const bf16x8*)&Cs[(wr * 64 + m * 16 + fr) * LDC + e0];
#pragma unroll
    for (int n = 0; n < 4; ++n)
      b2[n] = *(const bf16x8*)&relr[(wc * 64 + n * 16 + fr) * D_ + e0];
#pragma unroll
    for (int m = 0; m < 4; ++m)
#pragma unroll
      for (int n = 0; n < 4; ++n)
        tacc[m][n] = __builtin_amdgcn_mfma_f32_16x16x32_bf16(a2[m], b2[n], tacc[m][n], 0, 0, 0);
  }

  // mean over r (and K-split partials): atomic accumulate, scaled by 1/R
#pragma unroll
  for (int m = 0; m < 4; ++m)
#pragma unroll
    for (int n = 0; n < 4; ++n)
#pragma unroll
      for (int j = 0; j < 4; ++j) {
        int row = row0 + wr * 64 + m * 16 + cr4 + j;
        int col = wc * 64 + n * 16 + fr;
        atomicAdd(&out_acc[row * D_ + col], tacc[m][n][j] * 0.125f);
      }
}

extern "C" void kernel_launch(void* const* d_in, const int* in_sizes, int n_in,
                              void* d_out, int out_size, void* d_ws, size_t ws_size,
                              hipStream_t stream) {
  const float* adj = (const float*)d_in[0];   // [R][N][N]
  const float* emb = (const float*)d_in[1];   // [N][D]
  const float* rel = (const float*)d_in[2];   // [R][D][D]
  float* out = (float*)d_out;                 // [N][D] fp32, also the accumulator

  unsigned short* embT = (unsigned short*)d_ws;          // 1 MB:  [D][N] bf16
  unsigned short* relb = embT + (size_t)N_ * D_;         // 256KB: [R][D][D] bf16

  k_init_embT<<<(N_ * D_) / 256, 256, 0, stream>>>(emb, embT);
  k_init_rel<<<(R_ * D_ * D_) / 256, 256, 0, stream>>>(rel, relb);

  dim3 grid(N_ / BM, R_, KSPLIT);
  for (int layer = 0; layer < 2; ++layer) {
    hipMemsetAsync(out, 0, (size_t)N_ * D_ * sizeof(float), stream);
    gcn_gemm<<<grid, 256, 0, stream>>>(adj, embT, relb, out);
    k_epilogue<<<(N_ * D_) / 256, 256, 0, stream>>>(out, embT);
  }
}